// Round 17
// baseline (78.968 us; speedup 1.0000x reference)
//
#include <hip/hip_runtime.h>
#include <hip/hip_bf16.h>
#include <math.h>

#define B_   16
#define N_   32
#define I_   1152
#define DIN  16
#define D_   64
#define TI   16            // i's per k_xhat block
#define IB   (I_/TI)       // 72 i-tiles
#define IC   16            // i-chunks in routing (72 i each)
#define BND  (B_*N_*D_)    // 32768

#if __has_builtin(__builtin_amdgcn_exp2f)
#define EXP2(x) __builtin_amdgcn_exp2f(x)
#else
#define EXP2(x) exp2f(x)
#endif

#define LOG2E 1.4426950408889634f

typedef __attribute__((ext_vector_type(8))) short short8v;
typedef __attribute__((ext_vector_type(4))) float f32x4;
typedef __attribute__((ext_vector_type(4))) unsigned int u32x4;
typedef __attribute__((ext_vector_type(2))) unsigned int u32x2;

__device__ __forceinline__ float squash1(float s) {
    float sq = s * s;
    return (sq / (1.0f + sq)) * s * rsqrtf(sq + 1e-9f);
}
__device__ __forceinline__ float bff(unsigned int hi16) {
    return __builtin_bit_cast(float, hi16 << 16);
}
// HW packed fp32->bf16 RNE: dst[15:0]=bf16(a), dst[31:16]=bf16(b). 1 VALU op.
__device__ __forceinline__ unsigned int cvtpk(float a, float b) {
    unsigned int r;
    asm("v_cvt_pk_bf16_f32 %0, %1, %2" : "=v"(r) : "v"(a), "v"(b));
    return r;
}

// async global->LDS, 16B per lane, dest = uniform base + lane*16 (linear)
#define GL16(g, l) __builtin_amdgcn_global_load_lds(                          \
    (const __attribute__((address_space(1))) void*)(g),                       \
    (__attribute__((address_space(3))) void*)(l), 16, 0, 0)

// K1: x_hat via MFMA, DEEP-ISSUE W staging. All 16 gload_lds per wave
// (16KB/wave, 64KB/block) are fired before any wait; the input-tile staging
// runs UNDER the in-flight DMA; ONE __syncthreads drains; then all 16 i's
// are computed and stored. This is the counted-depth lesson (guide T3/T4):
// R12 drained every 4KB quarter at a barrier -> no gain; depth is the lever.
// 72KB LDS -> 2 blocks/CU; cross-block phase offset gives stage||compute.
// Swizzle (rule #21 both-sides, refcheck'd in R12): LDS[A]=orig[A^(((A>>7)&3)<<4)]
// via pre-swizzled per-lane SOURCE (linear dest), same XOR on ds_read.
// hi/lo W-residual: K 0..15 = W_hi (fp32 bit-truncation via v_perm),
// K 16..31 = W_lo residual (v_cvt_pk RNE), inputs duplicated -> fp32-grade W.
// C-frag: col b=l&15, d = mt*16+(l>>4)*4+r. xh2 tile: element off = mt*256+4l
// (lane-order: wave writes 512B contiguous per i).
__global__ __launch_bounds__(256) void k_xhat(const float* __restrict__ inp,
                                              const float* __restrict__ W,
                                              unsigned short* __restrict__ xh2,
                                              float* __restrict__ part) {
    __shared__ __align__(16) unsigned short xs[4096];   // inp tile bf16, swizzled (8KB)
    __shared__ __align__(16) float wls[16384];          // W tile, 16 i x 4KB (64KB)

    const int bx = blockIdx.x;
    const int n  = bx / IB;
    const int ib = bx % IB;
    const int i0 = ib * TI;
    const int t  = threadIdx.x;
    const int l  = t & 63;
    const int mt = t >> 6;                 // wave id = d m-tile (0..3)
    const int ko = (l >> 4) & 1;           // k-octet
    const bool loHalf = (l >= 32);
    const int dd = mt * 16 + (l & 15);     // this lane's d row in W
    const int A_OFF   = (dd * 64 + ko * 32) ^ (((dd >> 1) & 3) << 4);
    const int lane_sw = (l * 16) ^ (((l >> 3) & 3) << 4);   // inverse swizzle, src side

    const char* Wn = (const char*)(W + (size_t)(n * I_ + i0) * 1024);  // 64KB tile

    // ---- 1) fire ALL W DMA (16 gload_lds per wave; wave mt covers its
    //         1KB quarter of each of the 16 i-rows)
    #pragma unroll
    for (int r = 0; r < TI; ++r) {
        const char* g = Wn + (size_t)r * 4096 + mt * 1024 + lane_sw;
        char* ld = (char*)wls + r * 4096 + mt * 1024;
        GL16(g, ld);
    }

    // ---- 2) stage inputs -> bf16 LDS tile [b][il][ko][8], XOR-swizzled
    //         (runs while the W DMA is in flight)
    #pragma unroll
    for (int rep = 0; rep < 2; ++rep) {
        int s   = rep * 256 + t;           // 512 slots = 16b x 16il x 2ko
        int bb  = s >> 5;
        int il  = (s >> 1) & 15;
        int sko = s & 1;
        const float* src = inp + (size_t)bb * (I_ * DIN) + (size_t)(i0 + il) * DIN + sko * 8;
        f32x4 a0 = *(const f32x4*)src;
        f32x4 a1 = *(const f32x4*)(src + 4);
        u32x4 p;
        p.x = cvtpk(a0.x, a0.y);
        p.y = cvtpk(a0.z, a0.w);
        p.z = cvtpk(a1.x, a1.y);
        p.w = cvtpk(a1.z, a1.w);
        int base = (bb * 512 + il * 32 + sko * 16) ^ ((bb & 7) << 4);
        *(u32x4*)((char*)xs + base) = p;
    }
    __syncthreads();                       // single drain: W + inputs ready

    // ---- 3) compute all 16 i's
    unsigned int pk[TI * 2];
    f32x4 s0v = {0.f, 0.f, 0.f, 0.f};

    #pragma unroll
    for (int j = 0; j < TI; ++j) {
        f32x4 wk0 = *(const f32x4*)((const char*)wls + j * 4096 + A_OFF);
        f32x4 wk1 = *(const f32x4*)((const char*)wls + j * 4096 + (A_OFF ^ 16));
        u32x4 b0 = __builtin_bit_cast(u32x4, wk0);
        u32x4 b1 = __builtin_bit_cast(u32x4, wk1);
        u32x4 aw;
        if (!loHalf) {                     // hi = bit-truncation, packed by perm
            aw.x = __builtin_amdgcn_perm(b0.y, b0.x, 0x07060302u);
            aw.y = __builtin_amdgcn_perm(b0.w, b0.z, 0x07060302u);
            aw.z = __builtin_amdgcn_perm(b1.y, b1.x, 0x07060302u);
            aw.w = __builtin_amdgcn_perm(b1.w, b1.z, 0x07060302u);
        } else {                           // lo = RNE(w - trunc(w)) via cvt_pk
            float r0 = wk0.x - __builtin_bit_cast(float, b0.x & 0xffff0000u);
            float r1 = wk0.y - __builtin_bit_cast(float, b0.y & 0xffff0000u);
            float r2 = wk0.z - __builtin_bit_cast(float, b0.z & 0xffff0000u);
            float r3 = wk0.w - __builtin_bit_cast(float, b0.w & 0xffff0000u);
            float r4 = wk1.x - __builtin_bit_cast(float, b1.x & 0xffff0000u);
            float r5 = wk1.y - __builtin_bit_cast(float, b1.y & 0xffff0000u);
            float r6 = wk1.z - __builtin_bit_cast(float, b1.z & 0xffff0000u);
            float r7 = wk1.w - __builtin_bit_cast(float, b1.w & 0xffff0000u);
            aw.x = cvtpk(r0, r1);
            aw.y = cvtpk(r2, r3);
            aw.z = cvtpk(r4, r5);
            aw.w = cvtpk(r6, r7);
        }
        short8v afrag = __builtin_bit_cast(short8v, aw);
        int xaddr = ((l & 15) * 512 + j * 32 + ko * 16) ^ (((l & 15) & 7) << 4);
        short8v bfrag = *(const short8v*)((const char*)xs + xaddr);
        f32x4 acc = __builtin_amdgcn_mfma_f32_16x16x32_bf16(
            afrag, bfrag, (f32x4){0.f, 0.f, 0.f, 0.f}, 0, 0, 0);
        s0v += acc;
        pk[j * 2]     = cvtpk(acc[0], acc[1]);
        pk[j * 2 + 1] = cvtpk(acc[2], acc[3]);
    }

    // ---- 4) s0 partials (register-only), then fully-coalesced xh stores
    size_t pidx = (((size_t)ib * B_ + (l & 15)) * N_ + n) * 64 + mt * 16 + (l >> 4) * 4;
    *(f32x4*)(part + pidx) = s0v;

    #pragma unroll
    for (int i = 0; i < TI; ++i) {
        u32x2 v;
        v.x = pk[i * 2];
        v.y = pk[i * 2 + 1];
        size_t off = (size_t)(n * I_ + i0 + i) * 1024 + (size_t)t * 4;  // mt*256 + 4*l
        *reinterpret_cast<u32x2*>(xh2 + off) = v;
    }
}

// K2: coef = squash(mean over i of x_hat) — routing iteration 0.
// part layout [ib][b][n][d]; t packs (b,n,d) = coef index.
__global__ __launch_bounds__(256) void k_out0(const float* __restrict__ part,
                                              float* __restrict__ coef) {
    const int t = blockIdx.x * 256 + threadIdx.x;
    float s = 0.0f;
    for (int j = 0; j < IB; ++j) s += part[(size_t)j * BND + t];
    s *= (1.0f / (float)I_);
    coef[t] = squash1(s);
}

// K3: routing partial pass. xh2 tile is lane-ordered: thread t owns element
// offset 4t per i-tile => wave reads 512B CONTIGUOUS per i. Thread coords:
// b = t&15, d0 = (t>>4)*4. |logit|<=~50 -> exp2 safe without max-tracking.
// part2 layout [ic][n][b][d][2] = {z,a}.
__global__ __launch_bounds__(256) void k_rpart(const unsigned short* __restrict__ xh2,
                                               const float* __restrict__ coef,
                                               float* __restrict__ part2) {
    const int bx = blockIdx.x;
    const int n  = bx >> 4;
    const int ic = bx & 15;
    const int t  = threadIdx.x;
    const int b  = t & 15;
    const int d0 = (t >> 4) * 4;

    const unsigned short* base = xh2 + ((size_t)n * I_ + (size_t)ic * (I_ / IC)) * 1024
                               + (size_t)t * 4;
    f32x4 c4 = *(const f32x4*)(coef + ((size_t)b * N_ + n) * 64 + d0);
    float c2[4] = {c4.x * LOG2E, c4.y * LOG2E, c4.z * LOG2E, c4.w * LOG2E};
    float z[4] = {0, 0, 0, 0}, a[4] = {0, 0, 0, 0};

    #pragma unroll 8
    for (int i = 0; i < I_ / IC; ++i) {
        u32x2 u = *(const u32x2*)(base + (size_t)i * 1024);
        unsigned short s4[4] = {(unsigned short)(u.x & 0xffffu), (unsigned short)(u.x >> 16),
                                (unsigned short)(u.y & 0xffffu), (unsigned short)(u.y >> 16)};
        #pragma unroll
        for (int j = 0; j < 4; ++j) {
            float x = bff(s4[j]);
            float e = EXP2(x * c2[j]);
            z[j] += e;
            a[j] = fmaf(e, x, a[j]);
        }
    }

    size_t pidx = ((((size_t)ic * N_ + n) * 16 + b) * 64 + d0) * 2;
    f32x4 v0 = {z[0], a[0], z[1], a[1]};
    f32x4 v1 = {z[2], a[2], z[3], a[3]};
    *(f32x4*)(part2 + pidx)     = v0;
    *(f32x4*)(part2 + pidx + 4) = v1;
}

// K4: routing finisher. gid packs (n,b,d) matching part2 inner order.
// final=0: coef += squash(a/z). final=1: out[b][n][d] = squash(a/z).
__global__ __launch_bounds__(256) void k_rfin(const float* __restrict__ part2,
                                              const float* __restrict__ coefIn,
                                              float* __restrict__ outp,
                                              int final_) {
    const int gid = blockIdx.x * 256 + threadIdx.x;     // n*1024 + b*64 + d
    float Z = 0.0f, A = 0.0f;
    #pragma unroll
    for (int ic = 0; ic < IC; ++ic) {
        const float* p = part2 + ((size_t)ic * BND + gid) * 2;
        Z += p[0];
        A += p[1];
    }
    const int d = gid & 63, b = (gid >> 6) & 15, n = gid >> 10;
    const int ci = (b * N_ + n) * D_ + d;
    float o = squash1(A / Z);
    outp[ci] = final_ ? o : (coefIn[ci] + o);
}

extern "C" void kernel_launch(void* const* d_in, const int* in_sizes, int n_in,
                              void* d_out, int out_size, void* d_ws, size_t ws_size,
                              hipStream_t stream) {
    const float* inp = (const float*)d_in[0];
    const float* W   = (const float*)d_in[1];
    float* out = (float*)d_out;

    unsigned short* xh2 = (unsigned short*)d_ws;                    // 75,497,472 B
    float* part  = (float*)((char*)d_ws + 75497472);                //  9,437,184 B
    float* part2 = (float*)((char*)d_ws + 84934656);                //  4,194,304 B
    float* coef  = (float*)((char*)d_ws + 89128960);                //    131,072 B

    k_xhat<<<dim3(N_ * IB), dim3(256), 0, stream>>>(inp, W, xh2, part);
    k_out0<<<dim3(BND / 256), dim3(256), 0, stream>>>(part, coef);
    k_rpart<<<dim3(N_ * IC), dim3(256), 0, stream>>>(xh2, coef, part2);
    k_rfin <<<dim3(BND / 256), dim3(256), 0, stream>>>(part2, coef, coef, 0);
    k_rpart<<<dim3(N_ * IC), dim3(256), 0, stream>>>(xh2, coef, part2);
    k_rfin <<<dim3(BND / 256), dim3(256), 0, stream>>>(part2, coef, out, 1);
}